// Round 1
// 2368.292 us; speedup vs baseline: 1.2242x; 1.2242x over previous
//
#include <hip/hip_runtime.h>

// GRU scan: T=128, N=1024, H=512, I=64.
// LDS-free step kernel: both MFMA operand fragments (lane&15 row, (lane>>4)*8 k,
// contiguous half8) are loaded DIRECTLY from global (L1/L2-resident), so there
// are no barriers and the compiler can pipeline loads across the whole K loop.
// Operands are swapped vs the previous version: mfma(W_frag, h_frag, acc) puts
// 4 contiguous output COLUMNS per lane -> float4 epilogue loads/stores.
// h and x enter the GEMM pre-masked in fp16 (same rounding as before:
// fp32 h*m -> one fp16 round). The z*h*m epilogue term stays fp32.

#define T_STEPS 128
#define NBATCH  1024
#define HDIM    512
#define IDIM    64
#define KTOT    576

typedef _Float16 half8  __attribute__((ext_vector_type(8)));
typedef _Float16 half4  __attribute__((ext_vector_type(4)));
typedef float    floatx4 __attribute__((ext_vector_type(4)));

__global__ void prep_w_kernel(const float* __restrict__ Whh,
                              const float* __restrict__ Wih,
                              _Float16* __restrict__ W16) {
    int idx = blockIdx.x * 256 + threadIdx.x;
    if (idx >= 1536 * KTOT) return;
    int c = idx / KTOT;
    int k = idx - c * KTOT;
    float v = (k < HDIM) ? Whh[c * HDIM + k] : Wih[c * IDIM + (k - HDIM)];
    W16[idx] = (_Float16)v;
}

// x16m[t][n][i] = fp16( pact[t][n][i] * masks[t*N+n] )   (pre-masked input)
__global__ void prep_x_kernel(const float* __restrict__ pact,
                              const float* __restrict__ masks,
                              _Float16* __restrict__ x16) {
    int idx = blockIdx.x * 256 + threadIdx.x;
    if (idx >= T_STEPS * NBATCH * IDIM / 4) return;
    int e = idx * 4;
    float mk = masks[e >> 6];            // e/I, I=64 -> t*N+n
    floatx4 v = *(const floatx4*)(pact + e);
    half4 h;
    h[0] = (_Float16)(v.x * mk);
    h[1] = (_Float16)(v.y * mk);
    h[2] = (_Float16)(v.z * mk);
    h[3] = (_Float16)(v.w * mk);
    *(half4*)(x16 + e) = h;
}

// h16m[n][h] = fp16( hxs[n][h] * masks[n] )   (pre-masked h for step 0)
__global__ void prep_h_kernel(const float* __restrict__ hxs,
                              const float* __restrict__ masks,
                              _Float16* __restrict__ h16) {
    int idx = blockIdx.x * 256 + threadIdx.x;
    if (idx >= NBATCH * HDIM / 4) return;
    int e = idx * 4;
    float mk = masks[e >> 9];            // e/H, H=512 -> n
    floatx4 v = *(const floatx4*)(hxs + e);
    half4 h;
    h[0] = (_Float16)(v.x * mk);
    h[1] = (_Float16)(v.y * mk);
    h[2] = (_Float16)(v.z * mk);
    h[3] = (_Float16)(v.w * mk);
    *(half4*)(h16 + e) = h;
}

__device__ __forceinline__ float sigmoidf_(float x) {
    return 1.0f / (1.0f + __expf(-x));
}

#define MFMA16(a, b, c) __builtin_amdgcn_mfma_f32_16x16x32_f16((a), (b), (c), 0, 0, 0)

__global__ __launch_bounds__(128, 1)
void gru_step_kernel(const float* __restrict__ h_prev,     // [N,H] fp32 (out slot t-1, or hxs)
                     const _Float16* __restrict__ h16,     // [N,H] fp16 pre-masked: h_{t-1}*m_t
                     const _Float16* __restrict__ x16,     // [N,I] fp16 pre-masked: x_t*m_t
                     const float* __restrict__ m_t,        // [N]
                     const float* __restrict__ m_next,     // [N] masks for t+1, or null (last)
                     const _Float16* __restrict__ W16,     // [1536,576] fp16
                     const float* __restrict__ b_ih,       // [1536]
                     const float* __restrict__ b_hh,       // [1536]
                     float* __restrict__ out_x,            // [N,H] fp32
                     float* __restrict__ out_h,            // [N,H] fp32 or null
                     _Float16* __restrict__ h16_next) {    // [N,H] fp16 (pre-masked for t+1)
    const int tid  = threadIdx.x;
    const int wave = tid >> 6;          // 0..1
    const int lane = tid & 63;
    const int n16  = lane & 15;
    const int q    = lane >> 4;
    const int rowbase = (blockIdx.x >> 4) * 64 + wave * 32;  // wave's 32 batch rows
    const int colbase = (blockIdx.x & 15) * 32;              // 32 output cols

    floatx4 acc_r[2][2], acc_z[2][2], acc_hn[2][2], acc_in[2][2];
#pragma unroll
    for (int rs = 0; rs < 2; ++rs)
#pragma unroll
        for (int cs = 0; cs < 2; ++cs) {
            acc_r[rs][cs]  = (floatx4){0.f, 0.f, 0.f, 0.f};
            acc_z[rs][cs]  = (floatx4){0.f, 0.f, 0.f, 0.f};
            acc_hn[rs][cs] = (floatx4){0.f, 0.f, 0.f, 0.f};
            acc_in[rs][cs] = (floatx4){0.f, 0.f, 0.f, 0.f};
        }

    // Fragment pointers: both operands are (row = n16-indexed, k = q*8..q*8+7).
    const _Float16* hptr = h16 + (rowbase + n16) * HDIM + q * 8;
    const _Float16* wptr = W16 + (colbase + n16) * KTOT + q * 8;

    // ---- K = 0..511 : h part (gates r, z, and h_n accumulator)
#pragma unroll 4
    for (int kt = 0; kt < 16; ++kt) {
        half8 hf0 = *(const half8*)(hptr);
        half8 hf1 = *(const half8*)(hptr + 16 * HDIM);
        half8 wr0 = *(const half8*)(wptr);
        half8 wr1 = *(const half8*)(wptr + 16 * KTOT);
        half8 wz0 = *(const half8*)(wptr + HDIM * KTOT);
        half8 wz1 = *(const half8*)(wptr + (HDIM + 16) * KTOT);
        half8 wn0 = *(const half8*)(wptr + 2 * HDIM * KTOT);
        half8 wn1 = *(const half8*)(wptr + (2 * HDIM + 16) * KTOT);
        acc_r[0][0]  = MFMA16(wr0, hf0, acc_r[0][0]);
        acc_r[0][1]  = MFMA16(wr1, hf0, acc_r[0][1]);
        acc_r[1][0]  = MFMA16(wr0, hf1, acc_r[1][0]);
        acc_r[1][1]  = MFMA16(wr1, hf1, acc_r[1][1]);
        acc_z[0][0]  = MFMA16(wz0, hf0, acc_z[0][0]);
        acc_z[0][1]  = MFMA16(wz1, hf0, acc_z[0][1]);
        acc_z[1][0]  = MFMA16(wz0, hf1, acc_z[1][0]);
        acc_z[1][1]  = MFMA16(wz1, hf1, acc_z[1][1]);
        acc_hn[0][0] = MFMA16(wn0, hf0, acc_hn[0][0]);
        acc_hn[0][1] = MFMA16(wn1, hf0, acc_hn[0][1]);
        acc_hn[1][0] = MFMA16(wn0, hf1, acc_hn[1][0]);
        acc_hn[1][1] = MFMA16(wn1, hf1, acc_hn[1][1]);
        hptr += 32;
        wptr += 32;
    }

    // ---- K = 512..575 : x part (gates r, z, and i_n accumulator)
    const _Float16* xptr = x16 + (rowbase + n16) * IDIM + q * 8;
#pragma unroll
    for (int kt = 0; kt < 2; ++kt) {
        half8 hf0 = *(const half8*)(xptr);
        half8 hf1 = *(const half8*)(xptr + 16 * IDIM);
        half8 wr0 = *(const half8*)(wptr);
        half8 wr1 = *(const half8*)(wptr + 16 * KTOT);
        half8 wz0 = *(const half8*)(wptr + HDIM * KTOT);
        half8 wz1 = *(const half8*)(wptr + (HDIM + 16) * KTOT);
        half8 wn0 = *(const half8*)(wptr + 2 * HDIM * KTOT);
        half8 wn1 = *(const half8*)(wptr + (2 * HDIM + 16) * KTOT);
        acc_r[0][0]  = MFMA16(wr0, hf0, acc_r[0][0]);
        acc_r[0][1]  = MFMA16(wr1, hf0, acc_r[0][1]);
        acc_r[1][0]  = MFMA16(wr0, hf1, acc_r[1][0]);
        acc_r[1][1]  = MFMA16(wr1, hf1, acc_r[1][1]);
        acc_z[0][0]  = MFMA16(wz0, hf0, acc_z[0][0]);
        acc_z[0][1]  = MFMA16(wz1, hf0, acc_z[0][1]);
        acc_z[1][0]  = MFMA16(wz0, hf1, acc_z[1][0]);
        acc_z[1][1]  = MFMA16(wz1, hf1, acc_z[1][1]);
        acc_in[0][0] = MFMA16(wn0, hf0, acc_in[0][0]);
        acc_in[0][1] = MFMA16(wn1, hf0, acc_in[0][1]);
        acc_in[1][0] = MFMA16(wn0, hf1, acc_in[1][0]);
        acc_in[1][1] = MFMA16(wn1, hf1, acc_in[1][1]);
        xptr += 32;
        wptr += 32;
    }

    // ---- epilogue
    // Swapped-operand C/D layout: output col c = colbase + cs*16 + q*4 + r (contiguous
    // over r), batch row i = rowbase + rs*16 + n16 (fixed per lane) -> float4 I/O.
#pragma unroll
    for (int rs = 0; rs < 2; ++rs) {
        const int i = rowbase + rs * 16 + n16;
        const float mtv = m_t[i];
        const float mnv = m_next ? m_next[i] : 0.0f;
#pragma unroll
        for (int cs = 0; cs < 2; ++cs) {
            const int c0 = colbase + cs * 16 + q * 4;
            floatx4 bir = *(const floatx4*)(b_ih + c0);
            floatx4 bhr = *(const floatx4*)(b_hh + c0);
            floatx4 biz = *(const floatx4*)(b_ih + HDIM + c0);
            floatx4 bhz = *(const floatx4*)(b_hh + HDIM + c0);
            floatx4 bin = *(const floatx4*)(b_ih + 2 * HDIM + c0);
            floatx4 bhn = *(const floatx4*)(b_hh + 2 * HDIM + c0);
            floatx4 hp4 = *(const floatx4*)(h_prev + (size_t)i * HDIM + c0);
            floatx4 hv;
#pragma unroll
            for (int r = 0; r < 4; ++r) {
                const float rg = sigmoidf_(acc_r[rs][cs][r] + bir[r] + bhr[r]);
                const float zg = sigmoidf_(acc_z[rs][cs][r] + biz[r] + bhz[r]);
                const float ng = tanhf(acc_in[rs][cs][r] + bin[r] +
                                       rg * (acc_hn[rs][cs][r] + bhn[r]));
                hv[r] = (1.0f - zg) * ng + zg * (hp4[r] * mtv);
            }
            *(floatx4*)(out_x + (size_t)i * HDIM + c0) = hv;
            if (out_h) *(floatx4*)(out_h + (size_t)i * HDIM + c0) = hv;
            if (m_next) {
                half4 hh;
                hh[0] = (_Float16)(hv[0] * mnv);
                hh[1] = (_Float16)(hv[1] * mnv);
                hh[2] = (_Float16)(hv[2] * mnv);
                hh[3] = (_Float16)(hv[3] * mnv);
                *(half4*)(h16_next + (size_t)i * HDIM + c0) = hh;
            }
        }
    }
}

extern "C" void kernel_launch(void* const* d_in, const int* in_sizes, int n_in,
                              void* d_out, int out_size, void* d_ws, size_t ws_size,
                              hipStream_t stream) {
    const float* hxs   = (const float*)d_in[0];
    // d_in[1] = gru_init: dead code in the reference, unused
    const float* masks = (const float*)d_in[2];
    const float* pact  = (const float*)d_in[3];
    const float* W_ih  = (const float*)d_in[4];
    const float* W_hh  = (const float*)d_in[5];
    const float* b_ih  = (const float*)d_in[6];
    const float* b_hh  = (const float*)d_in[7];
    float* out = (float*)d_out;

    // workspace layout (fp16): W16 | x16m | h16m[2]   (~19.7 MB total)
    _Float16* W16  = (_Float16*)d_ws;                                  // 1536*576
    _Float16* x16  = W16 + 1536 * KTOT;                                // T*N*I
    _Float16* h16a = x16 + (size_t)T_STEPS * NBATCH * IDIM;            // N*H
    _Float16* h16b = h16a + (size_t)NBATCH * HDIM;                     // N*H

    const int wtot = 1536 * KTOT;
    prep_w_kernel<<<(wtot + 255) / 256, 256, 0, stream>>>(W_hh, W_ih, W16);
    const int xtot = T_STEPS * NBATCH * IDIM / 4;
    prep_x_kernel<<<(xtot + 255) / 256, 256, 0, stream>>>(pact, masks, x16);
    const int htot = NBATCH * HDIM / 4;
    prep_h_kernel<<<(htot + 255) / 256, 256, 0, stream>>>(hxs, masks, h16a);

    for (int t = 0; t < T_STEPS; ++t) {
        const float* h_prev =
            (t == 0) ? hxs : out + (size_t)(t - 1) * NBATCH * HDIM;
        const _Float16* hcur = (t & 1) ? h16b : h16a;
        _Float16* hnext      = (t & 1) ? h16a : h16b;
        const float* mnext =
            (t < T_STEPS - 1) ? masks + (size_t)(t + 1) * NBATCH : nullptr;
        float* out_x = out + (size_t)t * NBATCH * HDIM;
        float* out_h =
            (t == T_STEPS - 1) ? out + (size_t)T_STEPS * NBATCH * HDIM : nullptr;
        gru_step_kernel<<<256, 128, 0, stream>>>(
            h_prev, hcur, x16 + (size_t)t * NBATCH * IDIM,
            masks + (size_t)t * NBATCH, mnext, W16, b_ih, b_hh,
            out_x, out_h, hnext);
    }
}